// Round 9
// baseline (342.246 us; speedup 1.0000x reference)
//
#include <hip/hip_runtime.h>

typedef _Float16 f16;
typedef __attribute__((ext_vector_type(8))) _Float16 half8;
typedef __attribute__((ext_vector_type(4))) _Float16 half4;
typedef __attribute__((ext_vector_type(4))) float f32x4;

#define DEVINL static __device__ __forceinline__

constexpr float NORMALIZER = 0.35355339059327373f;  // 64^-0.25
constexpr float RATIO      = 0.08838834764831845f;  // 1/sqrt(128)
constexpr float FEPS       = 1e-6f;

// ---------------- workspace layout (bytes) ----------------
constexpr size_t OFF_WQKVT = 0;                                   // [2304][768] f16
constexpr size_t OFF_WOT   = OFF_WQKVT + (size_t)2304*768*2;      // [768][768] f16
constexpr size_t OFF_PROJF = OFF_WOT   + (size_t)768*768*2;       // [128][64] f16 (pre-scaled)
constexpr size_t OFF_KS    = OFF_PROJF + (size_t)128*64*2;        // [48][128] f32
constexpr size_t OFF_KSP   = OFF_KS    + (size_t)48*128*4;        // [48*64][128] f32
constexpr size_t OFF_KVST  = OFF_KSP   + (size_t)48*64*128*4;     // [48][64][128] f16
constexpr size_t OFF_CNT   = OFF_KVST  + (size_t)48*64*128*2;     // [48] int (+pad)
constexpr size_t OFF_KVSP  = OFF_CNT   + 4096;                    // [8][48][128][64] f32
constexpr size_t OFF_X16   = OFF_KVSP  + (size_t)8*48*128*64*4;   // [16384][768] f16
constexpr size_t OFF_ATT   = OFF_X16;                              // alias (x16 dead after QKV GEMM)
constexpr size_t OFF_Q16   = OFF_X16 + (size_t)16384*768*2;
constexpr size_t OFF_K16   = OFF_Q16 + (size_t)16384*768*2;
constexpr size_t OFF_VT    = OFF_K16 + (size_t)16384*768*2;       // [48][64][4096] f16
constexpr size_t OFF_KPT   = OFF_VT  + (size_t)16384*768*2;       // [48][128][4096] f16

// ---------------- helpers ----------------
DEVINL void gload_lds16(const f16* g, f16* lds) {
  __builtin_amdgcn_global_load_lds(
      (const __attribute__((address_space(1))) void*)g,
      (__attribute__((address_space(3))) void*)lds, 16, 0, 0);
}

#define VMCNT0    asm volatile("s_waitcnt vmcnt(0)" ::: "memory")
#define BAR       __builtin_amdgcn_s_barrier()

// =====================================================================
// 256x192 BK=32 double-buffered GEMM core, f16 in / f32 acc.
// (frozen at r8 best: 96.7us, MfmaUtil 25% — structure ceiling for K=768)
// =====================================================================
DEVINL void gemm256c(const f16* __restrict__ Ag, const f16* __restrict__ Bg,
                     f16* smem, f32x4 (&acc)[8][3], int w, int lane)
{
  constexpr int NT = 24;                 // 768 / 32
  const int wm = w >> 2, wn = w & 3;
  const int c = lane & 15, g16 = lane >> 4;
  const int tid = threadIdx.x;

#pragma unroll
  for (int i = 0; i < 8; ++i)
#pragma unroll
    for (int j = 0; j < 3; ++j)
      acc[i][j] = f32x4{0.f, 0.f, 0.f, 0.f};

  auto SA = [&](int tt, f16* buf) {      // A[256][32]: 1024 segs, 2/thread
#pragma unroll
    for (int u = 0; u < 2; ++u) {
      const int id = u * 512 + tid;
      const int r = id >> 2, sg = id & 3;
      const int seg = sg ^ ((r >> 1) & 3);
      gload_lds16(Ag + (size_t)r * 768 + tt * 32 + seg * 8, buf + (u * 512 + w * 64) * 8);
    }
  };
  auto SB = [&](int tt, f16* buf) {      // B[192][32]: 768 segs
    {
      const int r = tid >> 2, sg = tid & 3;
      const int seg = sg ^ ((r >> 1) & 3);
      gload_lds16(Bg + (size_t)r * 768 + tt * 32 + seg * 8, buf + 8192 + w * 64 * 8);
    }
    if (w < 4) {
      const int id = 512 + tid;
      const int r = id >> 2, sg = id & 3;
      const int seg = sg ^ ((r >> 1) & 3);
      gload_lds16(Bg + (size_t)r * 768 + tt * 32 + seg * 8, buf + 8192 + (512 + w * 64) * 8);
    }
  };
  auto RDA = [&](const f16* buf, int mh, half8 (&av)[4]) {
#pragma unroll
    for (int i = 0; i < 4; ++i) {
      const int r = wm * 128 + mh * 64 + i * 16 + c;
      av[i] = *(const half8*)(buf + r * 32 + ((g16 ^ ((r >> 1) & 3)) << 3));
    }
  };
  auto RDB = [&](const f16* buf, half8 (&bv)[3]) {
#pragma unroll
    for (int j = 0; j < 3; ++j) {
      const int r = wn * 48 + j * 16 + c;
      bv[j] = *(const half8*)(buf + 8192 + r * 32 + ((g16 ^ ((r >> 1) & 3)) << 3));
    }
  };

  // prologue
  SA(0, smem); SB(0, smem);
  VMCNT0;
  BAR;

#pragma unroll 1
  for (int t = 0; t < NT; ++t) {
    f16* bufR = smem + (t & 1) * 14336;
    f16* bufW = smem + ((t & 1) ^ 1) * 14336;
    const bool st = (t + 1) < NT;
    half8 av[4], bv[3];

    RDA(bufR, 0, av); RDB(bufR, bv);
    if (st) SA(t + 1, bufW);
    __builtin_amdgcn_s_setprio(1);
#pragma unroll
    for (int i = 0; i < 4; ++i)
#pragma unroll
      for (int j = 0; j < 3; ++j)
        acc[i][j] = __builtin_amdgcn_mfma_f32_16x16x32_f16(av[i], bv[j], acc[i][j], 0, 0, 0);
    __builtin_amdgcn_s_setprio(0);
    RDA(bufR, 1, av);
    if (st) SB(t + 1, bufW);
    __builtin_amdgcn_s_setprio(1);
#pragma unroll
    for (int i = 0; i < 4; ++i)
#pragma unroll
      for (int j = 0; j < 3; ++j)
        acc[4 + i][j] = __builtin_amdgcn_mfma_f32_16x16x32_f16(av[i], bv[j], acc[4 + i][j], 0, 0, 0);
    __builtin_amdgcn_s_setprio(0);
    VMCNT0;
    BAR;
  }
}

// ---------------- QKV GEMM (writes Q,K normal; V transposed) ----------------
__global__ __launch_bounds__(512, 2) void k_gemm_qkv8(const f16* __restrict__ X16, const f16* __restrict__ WT,
    const float* __restrict__ bq, const float* __restrict__ bk, const float* __restrict__ bv,
    f16* __restrict__ Qo, f16* __restrict__ Ko, f16* __restrict__ VT)
{
  __shared__ f16 smem[28672];            // 56 KiB
  f32x4 acc[8][3];
  const int lin = blockIdx.x;
  const int xcd = lin & 7, chunk = lin >> 3;      // [0,96)
  const int bx = xcd * 8 + chunk / 12;            // [0,64)
  const int by = chunk % 12;                      // [0,12)
  const int brow0 = bx * 256;
  const int t = threadIdx.x, w = t >> 6, lane = t & 63;
  gemm256c(X16 + (size_t)brow0 * 768, WT + (size_t)by * 192 * 768, smem, acc, w, lane);

  const int wm = w >> 2, wn = w & 3;
  const int c = lane & 15, g16 = lane >> 4;
  const int which = by >> 2;             // 0:q 1:k 2:v
  const int colhdr = (by & 3) * 192;
  const float* bias = which == 0 ? bq : (which == 1 ? bk : bv);
  float bb[3];
#pragma unroll
  for (int j = 0; j < 3; ++j) bb[j] = bias[colhdr + wn * 48 + j * 16 + c];

  f16* ep = smem;
  if (which < 2) {
    f16* QK = which == 0 ? Qo : Ko;
#pragma unroll 1
    for (int p = 0; p < 2; ++p) {
      __syncthreads();
      if (wm == p) {
#pragma unroll
        for (int ii = 0; ii < 8; ++ii)
#pragma unroll
          for (int j = 0; j < 3; ++j)
#pragma unroll
            for (int r = 0; r < 4; ++r)
              ep[((ii >> 2) * 64 + (ii & 3) * 16 + g16 * 4 + r) * 200 + wn * 48 + j * 16 + c]
                  = (f16)(acc[ii][j][r] + bb[j]);
      }
      __syncthreads();
      const int row = t >> 2, sg = (t & 3) * 48;
      f16* dst = QK + (size_t)(brow0 + p * 128 + row) * 768 + colhdr + sg;
      const f16* sp = ep + row * 200 + sg;
#pragma unroll
      for (int u = 0; u < 6; ++u) *(half8*)(dst + u * 8) = *(const half8*)(sp + u * 8);
    }
  } else {
    const int bIdx = brow0 >> 12;
#pragma unroll 1
    for (int p = 0; p < 2; ++p) {
      __syncthreads();
      if (wm == p) {
#pragma unroll
        for (int ii = 0; ii < 8; ++ii)
#pragma unroll
          for (int j = 0; j < 3; ++j)
#pragma unroll
            for (int r = 0; r < 4; ++r)
              ep[(wn * 48 + j * 16 + c) * 136 + (ii >> 2) * 64 + (ii & 3) * 16 + g16 * 4 + r]
                  = (f16)(acc[ii][j][r] + bb[j]);
      }
      __syncthreads();
      if (t < 384) {
        const int cl = t >> 1, sg = (t & 1) * 64;
        const int vcol = colhdr + cl;
        const int h = vcol >> 6, d = vcol & 63;
        f16* dst = VT + ((size_t)(bIdx * 12 + h) * 64 + d) * 4096 + (brow0 & 4095) + p * 128 + sg;
        const f16* sp = ep + cl * 136 + sg;
#pragma unroll
        for (int u = 0; u < 8; ++u) *(half8*)(dst + u * 8) = *(const half8*)(sp + u * 8);
      }
    }
  }
}

// ---------------- final GEMM ----------------
__global__ __launch_bounds__(512, 2) void k_gemm_out8(const f16* __restrict__ ATT, const f16* __restrict__ WOT,
    const float* __restrict__ bo, float* __restrict__ out)
{
  __shared__ f16 smem[28672];
  f32x4 acc[8][3];
  const int lin = blockIdx.x;
  const int xcd = lin & 7, chunk = lin >> 3;      // [0,32)
  const int bx = xcd * 8 + (chunk >> 2);          // [0,64)
  const int by = chunk & 3;                       // [0,4)
  const int brow0 = bx * 256;
  const int t = threadIdx.x, w = t >> 6, lane = t & 63;
  gemm256c(ATT + (size_t)brow0 * 768, WOT + (size_t)by * 192 * 768, smem, acc, w, lane);

  const int wm = w >> 2, wn = w & 3;
  const int c = lane & 15, g16 = lane >> 4;
  float bb[3];
#pragma unroll
  for (int j = 0; j < 3; ++j) bb[j] = bo[by * 192 + wn * 48 + j * 16 + c];
#pragma unroll
  for (int ii = 0; ii < 8; ++ii) {
    const int row0 = brow0 + wm * 128 + (ii >> 2) * 64 + (ii & 3) * 16 + g16 * 4;
#pragma unroll
    for (int j = 0; j < 3; ++j) {
      const int col = by * 192 + wn * 48 + j * 16 + c;
#pragma unroll
      for (int r = 0; r < 4; ++r)
        out[(size_t)(row0 + r) * 768 + col] = acc[ii][j][r] + bb[j];
    }
  }
}

// =====================================================================
// 128-tile GEMM core (kept for kvs)
// =====================================================================
template<int BN>
DEVINL void gemm_tile(const f16* A, int lda, const f16* Bt, int ldb, int K,
                      f16* As, f16* Bs, f32x4 (&acc)[4][BN/32])
{
  constexpr int NF = BN/32;
  const int t = threadIdx.x;
  const int w = t >> 6, lane = t & 63;
  const int g = lane >> 4, c = lane & 15;
  const int wr = w >> 1, wc = w & 1;
  const int srow = lane >> 2;
  const int sseg = (lane & 3) * 8;

#pragma unroll
  for (int i = 0; i < 4; ++i)
#pragma unroll
    for (int j = 0; j < NF; ++j)
      acc[i][j] = f32x4{0.f, 0.f, 0.f, 0.f};

  for (int k0 = 0; k0 < K; k0 += 32) {
#pragma unroll
    for (int r = 0; r < 2; ++r) {
      const int rowblk = (w + 4*r) * 16;
      gload_lds16(A + (size_t)(rowblk + srow) * lda + k0 + sseg, As + rowblk*32);
    }
#pragma unroll
    for (int r = 0; r < BN/64; ++r) {
      const int rowblk = (w + 4*r) * 16;
      gload_lds16(Bt + (size_t)(rowblk + srow) * ldb + k0 + sseg, Bs + rowblk*32);
    }
    __syncthreads();
    half8 av[4], bv[NF];
#pragma unroll
    for (int i = 0; i < 4; ++i)
      av[i] = *(const half8*)(As + (wr*64 + i*16 + c)*32 + g*8);
#pragma unroll
    for (int j = 0; j < NF; ++j)
      bv[j] = *(const half8*)(Bs + (wc*(BN/2) + j*16 + c)*32 + g*8);
#pragma unroll
    for (int i = 0; i < 4; ++i)
#pragma unroll
      for (int j = 0; j < NF; ++j)
        acc[i][j] = __builtin_amdgcn_mfma_f32_16x16x32_f16(av[i], bv[j], acc[i][j], 0, 0, 0);
    __syncthreads();
  }
}

// ---------------- cast / transpose kernels ----------------
__global__ __launch_bounds__(256) void k_cast_x(const float* __restrict__ X, f16* __restrict__ X16,
    const float* __restrict__ P, f16* __restrict__ PF, int* __restrict__ CNT)
{
  const size_t i = ((size_t)blockIdx.x*256 + threadIdx.x) * 4;
  const float4 v = *(const float4*)(X + i);
  half4 h;
  h[0] = (f16)v.x; h[1] = (f16)v.y; h[2] = (f16)v.z; h[3] = (f16)v.w;
  *(half4*)(X16 + i) = h;
  if (blockIdx.x == 0) {                  // fold in proj cast + counter zero
    for (int i2 = threadIdx.x; i2 < 8192; i2 += 256) PF[i2] = (f16)(NORMALIZER * P[i2]);
    if (threadIdx.x < 48) CNT[threadIdx.x] = 0;
  }
}

__global__ __launch_bounds__(256) void k_transpose_w4(const float* __restrict__ Wq, const float* __restrict__ Wk,
    const float* __restrict__ Wv, const float* __restrict__ Wo, f16* __restrict__ WQKVT, f16* __restrict__ WOT)
{
  __shared__ float ls[64][65];
  const int t = threadIdx.x;
  const int k0 = blockIdx.x*64, n0 = blockIdx.y*64, z = blockIdx.z;
  const float* W = z == 0 ? Wq : (z == 1 ? Wk : (z == 2 ? Wv : Wo));
  f16* Wt = z < 3 ? (WQKVT + (size_t)z*768*768) : WOT;
#pragma unroll
  for (int it = 0; it < 4; ++it) {
    const int r = it*16 + (t >> 4);
    const int cs = (t & 15) * 4;
    const float4 v = *(const float4*)(W + (size_t)(k0 + r)*768 + n0 + cs);
    ls[r][cs+0] = v.x; ls[r][cs+1] = v.y; ls[r][cs+2] = v.z; ls[r][cs+3] = v.w;
  }
  __syncthreads();
  const int n = t >> 2;
  const int seg = (t & 3) * 16;
  half8 ov[2];
#pragma unroll
  for (int i = 0; i < 16; ++i) ov[i>>3][i&7] = (f16)ls[seg + i][n];
  f16* dst = Wt + (size_t)(n0 + n)*768 + k0 + seg;
  *(half8*)dst = ov[0];
  *(half8*)(dst + 8) = ov[1];
}

// ---------------- feature kernels ----------------
DEVINL void feat_common(const f16* base, const f16* PROJF,
                        f16* qs, f16* ps, float* dd, float* diag_s)
{
  const int t = threadIdx.x, w = t >> 6, lane = t & 63;
#pragma unroll
  for (int it = 0; it < 2; ++it) {
    const int rowblk = it*32 + w*8;
    gload_lds16(base + (size_t)(rowblk + (lane>>3))*768 + (lane&7)*8, qs + rowblk*64);
  }
#pragma unroll
  for (int it = 0; it < 4; ++it) {
    const int rowblk = it*32 + w*8;
    gload_lds16(PROJF + (size_t)(rowblk + (lane>>3))*64 + (lane&7)*8, ps + rowblk*64);
  }
  __syncthreads();
  {
    // diag: all 256 lanes (4 lanes per row, 16 elems each, shfl-combine)
    const int row = t >> 2, q = t & 3;
    const f16* kr = qs + row*64 + q*16;
    half8 v0 = *(const half8*)(kr);
    half8 v1 = *(const half8*)(kr + 8);
    float s = 0.f;
#pragma unroll
    for (int d2 = 0; d2 < 8; ++d2) { float a = (float)v0[d2]; s += a*a; }
#pragma unroll
    for (int d2 = 0; d2 < 8; ++d2) { float a = (float)v1[d2]; s += a*a; }
    s += __shfl_xor(s, 1);
    s += __shfl_xor(s, 2);
    if (q == 0) diag_s[row] = 0.0625f * s;
  }
  const int g = lane >> 4, c = lane & 15;
  const int wr = w >> 1, wc = w & 1;
  f32x4 facc[2][4];
#pragma unroll
  for (int i = 0; i < 2; ++i)
#pragma unroll
    for (int j = 0; j < 4; ++j) facc[i][j] = f32x4{0.f,0.f,0.f,0.f};
#pragma unroll
  for (int kk = 0; kk < 2; ++kk) {
    half8 av[2], bv[4];
#pragma unroll
    for (int i = 0; i < 2; ++i) av[i] = *(const half8*)(qs + (wr*32 + i*16 + c)*64 + kk*32 + g*8);
#pragma unroll
    for (int j = 0; j < 4; ++j) bv[j] = *(const half8*)(ps + (wc*64 + j*16 + c)*64 + kk*32 + g*8);
#pragma unroll
    for (int i = 0; i < 2; ++i)
#pragma unroll
      for (int j = 0; j < 4; ++j)
        facc[i][j] = __builtin_amdgcn_mfma_f32_16x16x32_f16(av[i], bv[j], facc[i][j], 0, 0, 0);
  }
#pragma unroll
  for (int i = 0; i < 2; ++i)
#pragma unroll
    for (int j = 0; j < 4; ++j)
#pragma unroll
      for (int r = 0; r < 4; ++r)
        dd[(wr*32 + i*16 + g*4 + r)*129 + wc*64 + j*16 + c] = facc[i][j][r];
  __syncthreads();
}

__global__ __launch_bounds__(256) void k_kfeat(const f16* __restrict__ Kin, const f16* __restrict__ PROJF,
    f16* __restrict__ KPT, float* __restrict__ KSP)
{
  __shared__ f16 qs[64*64];
  __shared__ f16 ps[128*64];
  __shared__ float dd[64*129];
  __shared__ float diag_s[64];
  const int t = threadIdx.x;
  const int lb = blockIdx.x, bh = blockIdx.y;
  const int b = bh / 12, h = bh - b*12;
  feat_common(Kin + ((size_t)(b*4096 + lb*64))*768 + h*64, PROJF, qs, ps, dd, diag_s);
  const int l = t >> 2, s = t & 3;
  float v[32];
#pragma unroll
  for (int j = 0; j < 32; ++j) v[j] = dd[l*129 + s*32 + j];
  float mx = v[0];
#pragma unroll
  for (int j = 1; j < 32; ++j) mx = fmaxf(mx, v[j]);
  mx = fmaxf(mx, __shfl_xor(mx, 1));
  mx = fmaxf(mx, __shfl_xor(mx, 2));
  const float off = diag_s[l] + mx;
#pragma unroll
  for (int j = 0; j < 32; ++j) dd[l*129 + s*32 + j] = RATIO * (__expf(v[j] - off) + FEPS);
  __syncthreads();
  {
    // KSP column-sum: all 256 lanes (2 per column, 32 rows each, shfl)
    const int m = t >> 1, hf = t & 1;
    float sm = 0.f;
#pragma unroll 8
    for (int l2 = hf*32; l2 < hf*32 + 32; ++l2) sm += dd[l2*129 + m];
    sm += __shfl_xor(sm, 1);
    if (hf == 0) KSP[((size_t)bh*64 + lb)*128 + m] = sm;
  }
  const int m = t >> 1, hf = t & 1;
  half8 ov[4];
#pragma unroll
  for (int i2 = 0; i2 < 32; ++i2) ov[i2>>3][i2&7] = (f16)dd[(hf*32 + i2)*129 + m];
  f16* dst = KPT + ((size_t)bh*128 + m)*4096 + lb*64 + hf*32;
#pragma unroll
  for (int q8 = 0; q8 < 4; ++q8) *(half8*)(dst + q8*8) = ov[q8];
}

// ---------------- kvs (+ fused fan-in reduce) ----------------
__global__ __launch_bounds__(256) void k_kvs(const f16* __restrict__ KPT, const f16* __restrict__ VT,
    float* __restrict__ KVSP, const float* __restrict__ KSP, f16* __restrict__ KVST,
    float* __restrict__ KS, int* __restrict__ CNT)
{
  __shared__ f16 As[128*32], Bs[64*32];
  f32x4 acc[4][2];
  const int chunk = blockIdx.x, bh = blockIdx.y;   // (8, 48)
  gemm_tile<64>(KPT + (size_t)bh*128*4096 + chunk*512, 4096,
                VT  + (size_t)bh*64*4096  + chunk*512, 4096, 512, As, Bs, acc);
  const int t = threadIdx.x, w = t>>6, lane = t&63, g = lane>>4, c = lane&15;
  const int wr = w>>1, wc = w&1;
  float* dst = KVSP + (size_t)(chunk*48 + bh)*128*64;
#pragma unroll
  for (int i = 0; i < 4; ++i) {
    const int row0 = wr*64 + i*16 + g*4;
#pragma unroll
    for (int j = 0; j < 2; ++j) {
      const int col = wc*32 + j*16 + c;
#pragma unroll
      for (int r = 0; r < 4; ++r) dst[(size_t)(row0 + r)*64 + col] = acc[i][j][r];
    }
  }

  // ---- split-K fan-in: last block per bh reduces (deterministic order) ----
  __threadfence();                       // release partials to device scope
  __syncthreads();
  __shared__ int lastFlag;
  if (t == 0) lastFlag = (atomicAdd(&CNT[bh], 1) == 7);
  __syncthreads();
  if (lastFlag) {
    __threadfence();                     // acquire: invalidate stale lines
    for (int i = t; i < 128*64; i += 256) {
      const int m = i >> 6, d = i & 63;
      float s = 0.f;
#pragma unroll
      for (int c2 = 0; c2 < 8; ++c2) s += KVSP[((size_t)(c2*48 + bh)*128 + m)*64 + d];
      KVST[((size_t)bh*64 + d)*128 + m] = (f16)s;
    }
    for (int i = t; i < 128; i += 256) {
      float s = 0.f;
#pragma unroll 8
      for (int lb = 0; lb < 64; ++lb) s += KSP[((size_t)bh*64 + lb)*128 + i];
      KS[bh*128 + i] = s;
    }
  }
}

// ---------------- fused q-feature + num GEMM + normalize -> ATT ----------------
__global__ __launch_bounds__(256) void k_qfn(const f16* __restrict__ Q, const f16* __restrict__ PROJF,
    const float* __restrict__ KS, const f16* __restrict__ KVST, f16* __restrict__ ATT)
{
  __shared__ f16 qs[64*64];
  __shared__ f16 ps[128*64];
  __shared__ float dd[64*129];
  __shared__ float diag_s[64];
  __shared__ float den_s[64];
  __shared__ f16 qp[64*128];
  __shared__ float ks_s[128];
  const int t = threadIdx.x;
  const int lb = blockIdx.x, bh = blockIdx.y;
  const int b = bh / 12, h = bh - b*12;
  if (t < 128) ks_s[t] = KS[bh*128 + t];
  feat_common(Q + ((size_t)(b*4096 + lb*64))*768 + h*64, PROJF, qs, ps, dd, diag_s);

  const int w = t >> 6, lane = t & 63, g16 = lane >> 4, c = lane & 15;
  const int wr = w >> 1, wc = w & 1;
  half8 bv2[2][4];
#pragma unroll
  for (int j = 0; j < 2; ++j) {
    const int d = wc*32 + j*16 + c;
#pragma unroll
    for (int kk = 0; kk < 4; ++kk)
      bv2[j][kk] = *(const half8*)(KVST + (size_t)bh*8192 + d*128 + kk*32 + g16*8);
  }

  const int l = t >> 2, s = t & 3;
  float v[32];
#pragma unroll
  for (int j = 0; j < 32; ++j) v[j] = dd[l*129 + s*32 + j];
  float mx = v[0];
#pragma unroll
  for (int j = 1; j < 32; ++j) mx = fmaxf(mx, v[j]);
  mx = fmaxf(mx, __shfl_xor(mx, 1));
  mx = fmaxf(mx, __shfl_xor(mx, 2));
  const float off = diag_s[l] + mx;
  half8 ov[4];
  float dp = 0.f;
#pragma unroll
  for (int j = 0; j < 32; ++j) {
    const float e = RATIO * (__expf(v[j] - off) + FEPS);
    ov[j>>3][j&7] = (f16)e;
    dp += e * ks_s[s*32 + j];
  }
  dp += __shfl_xor(dp, 1);
  dp += __shfl_xor(dp, 2);
  if (s == 0) den_s[l] = dp;
#pragma unroll
  for (int k = 0; k < 4; ++k)
    *(half8*)(qp + l*128 + (((4*s + k) ^ (l & 7)) << 3)) = ov[k];
  __syncthreads();

  f32x4 acc2[2][2];
#pragma unroll
  for (int i = 0; i < 2; ++i)
#pragma unroll
    for (int j = 0; j < 2; ++j) acc2[i][j] = f32x4{0.f,0.f,0.f,0.f};
#pragma unroll
  for (int kk = 0; kk < 4; ++kk) {
    half8 av2[2];
#pragma unroll
    for (int i = 0; i < 2; ++i) {
      const int l2 = wr*32 + i*16 + c;
      av2[i] = *(const half8*)(qp + l2*128 + (((kk*4 + g16) ^ (l2 & 7)) << 3));
    }
#pragma unroll
    for (int i = 0; i < 2; ++i)
#pragma unroll
      for (int j = 0; j < 2; ++j)
        acc2[i][j] = __builtin_amdgcn_mfma_f32_16x16x32_f16(av2[i], bv2[j][kk], acc2[i][j], 0, 0, 0);
  }

  f16* ep = ps;   // [64][72]
#pragma unroll
  for (int i = 0; i < 2; ++i)
#pragma unroll
    for (int j = 0; j < 2; ++j)
#pragma unroll
      for (int r = 0; r < 4; ++r) {
        const int l3 = wr*32 + i*16 + g16*4 + r;
        ep[l3*72 + wc*32 + j*16 + c] = (f16)(acc2[i][j][r] / den_s[l3]);
      }
  __syncthreads();
  const int row = t >> 2, sg = (t & 3) * 16;
  f16* dst = ATT + ((size_t)bh*4096 + lb*64 + row)*64 + sg;
  const f16* sp = ep + row*72 + sg;
  *(half8*)dst = *(const half8*)sp;
  *(half8*)(dst + 8) = *(const half8*)(sp + 8);
}

// ---------------- launcher ----------------
extern "C" void kernel_launch(void* const* d_in, const int* in_sizes, int n_in,
                              void* d_out, int out_size, void* d_ws, size_t ws_size,
                              hipStream_t stream)
{
  const float* x    = (const float*)d_in[0];
  const float* Wq   = (const float*)d_in[1];
  const float* bq   = (const float*)d_in[2];
  const float* Wk   = (const float*)d_in[3];
  const float* bk   = (const float*)d_in[4];
  const float* Wv   = (const float*)d_in[5];
  const float* bv   = (const float*)d_in[6];
  const float* Wo   = (const float*)d_in[7];
  const float* bo   = (const float*)d_in[8];
  const float* proj = (const float*)d_in[9];
  float* out = (float*)d_out;
  char* ws = (char*)d_ws;

  f16*   WQKVT = (f16*)(ws + OFF_WQKVT);
  f16*   WOT   = (f16*)(ws + OFF_WOT);
  f16*   PROJF = (f16*)(ws + OFF_PROJF);
  float* KS    = (float*)(ws + OFF_KS);
  float* KSP   = (float*)(ws + OFF_KSP);
  f16*   KVST  = (f16*)(ws + OFF_KVST);
  int*   CNT   = (int*)(ws + OFF_CNT);
  float* KVSP  = (float*)(ws + OFF_KVSP);
  f16*   X16   = (f16*)(ws + OFF_X16);
  f16*   ATT   = (f16*)(ws + OFF_ATT);
  f16*   Q16   = (f16*)(ws + OFF_Q16);
  f16*   K16   = (f16*)(ws + OFF_K16);
  f16*   VT    = (f16*)(ws + OFF_VT);
  f16*   KPT   = (f16*)(ws + OFF_KPT);

  k_cast_x<<<12288, 256, 0, stream>>>(x, X16, proj, PROJF, CNT);
  k_transpose_w4<<<dim3(12,12,4), 256, 0, stream>>>(Wq, Wk, Wv, Wo, WQKVT, WOT);

  k_gemm_qkv8<<<768, 512, 0, stream>>>(X16, WQKVT, bq, bk, bv, Q16, K16, VT);
  k_kfeat<<<dim3(64,48), 256, 0, stream>>>(K16, PROJF, KPT, KSP);
  k_kvs<<<dim3(8,48), 256, 0, stream>>>(KPT, VT, KVSP, KSP, KVST, KS, CNT);
  k_qfn<<<dim3(64,48), 256, 0, stream>>>(Q16, PROJF, KS, KVST, ATT);
  k_gemm_out8<<<256, 512, 0, stream>>>(ATT, WOT, bo, out);
}

// Round 10
// 246.149 us; speedup vs baseline: 1.3904x; 1.3904x over previous
//
#include <hip/hip_runtime.h>

typedef _Float16 f16;
typedef __attribute__((ext_vector_type(8))) _Float16 half8;
typedef __attribute__((ext_vector_type(4))) _Float16 half4;
typedef __attribute__((ext_vector_type(4))) float f32x4;

#define DEVINL static __device__ __forceinline__

constexpr float NORMALIZER = 0.35355339059327373f;  // 64^-0.25
constexpr float RATIO      = 0.08838834764831845f;  // 1/sqrt(128)
constexpr float FEPS       = 1e-6f;

// ---------------- workspace layout (bytes) ----------------
constexpr size_t OFF_WQKVT = 0;                                   // [2304][768] f16
constexpr size_t OFF_WOT   = OFF_WQKVT + (size_t)2304*768*2;      // [768][768] f16
constexpr size_t OFF_PROJF = OFF_WOT   + (size_t)768*768*2;       // [128][64] f16 (pre-scaled)
constexpr size_t OFF_KS    = OFF_PROJF + (size_t)128*64*2;        // [48][128] f32
constexpr size_t OFF_KSP   = OFF_KS    + (size_t)48*128*4;        // [48*64][128] f32
constexpr size_t OFF_KVST  = OFF_KSP   + (size_t)48*64*128*4;     // [48][64][128] f16
constexpr size_t OFF_KVSP  = OFF_KVST  + (size_t)48*64*128*2;     // [8][48][128][64] f32
constexpr size_t OFF_X16   = OFF_KVSP  + (size_t)8*48*128*64*4;   // [16384][768] f16
constexpr size_t OFF_ATT   = OFF_X16;                              // alias (x16 dead after QKV GEMM)
constexpr size_t OFF_Q16   = OFF_X16 + (size_t)16384*768*2;
constexpr size_t OFF_K16   = OFF_Q16 + (size_t)16384*768*2;
constexpr size_t OFF_VT    = OFF_K16 + (size_t)16384*768*2;       // [48][64][4096] f16
constexpr size_t OFF_KPT   = OFF_VT  + (size_t)16384*768*2;       // [48][128][4096] f16

// ---------------- helpers ----------------
DEVINL void gload_lds16(const f16* g, f16* lds) {
  __builtin_amdgcn_global_load_lds(
      (const __attribute__((address_space(1))) void*)g,
      (__attribute__((address_space(3))) void*)lds, 16, 0, 0);
}

#define VMCNT0    asm volatile("s_waitcnt vmcnt(0)" ::: "memory")
#define BAR       __builtin_amdgcn_s_barrier()

// =====================================================================
// 256x192 BK=32 double-buffered GEMM core, f16 in / f32 acc.
// (frozen at r8 best: 96.7us, MfmaUtil 25% — structure ceiling for K=768)
// =====================================================================
DEVINL void gemm256c(const f16* __restrict__ Ag, const f16* __restrict__ Bg,
                     f16* smem, f32x4 (&acc)[8][3], int w, int lane)
{
  constexpr int NT = 24;                 // 768 / 32
  const int wm = w >> 2, wn = w & 3;
  const int c = lane & 15, g16 = lane >> 4;
  const int tid = threadIdx.x;

#pragma unroll
  for (int i = 0; i < 8; ++i)
#pragma unroll
    for (int j = 0; j < 3; ++j)
      acc[i][j] = f32x4{0.f, 0.f, 0.f, 0.f};

  auto SA = [&](int tt, f16* buf) {      // A[256][32]: 1024 segs, 2/thread
#pragma unroll
    for (int u = 0; u < 2; ++u) {
      const int id = u * 512 + tid;
      const int r = id >> 2, sg = id & 3;
      const int seg = sg ^ ((r >> 1) & 3);
      gload_lds16(Ag + (size_t)r * 768 + tt * 32 + seg * 8, buf + (u * 512 + w * 64) * 8);
    }
  };
  auto SB = [&](int tt, f16* buf) {      // B[192][32]: 768 segs
    {
      const int r = tid >> 2, sg = tid & 3;
      const int seg = sg ^ ((r >> 1) & 3);
      gload_lds16(Bg + (size_t)r * 768 + tt * 32 + seg * 8, buf + 8192 + w * 64 * 8);
    }
    if (w < 4) {
      const int id = 512 + tid;
      const int r = id >> 2, sg = id & 3;
      const int seg = sg ^ ((r >> 1) & 3);
      gload_lds16(Bg + (size_t)r * 768 + tt * 32 + seg * 8, buf + 8192 + (512 + w * 64) * 8);
    }
  };
  auto RDA = [&](const f16* buf, int mh, half8 (&av)[4]) {
#pragma unroll
    for (int i = 0; i < 4; ++i) {
      const int r = wm * 128 + mh * 64 + i * 16 + c;
      av[i] = *(const half8*)(buf + r * 32 + ((g16 ^ ((r >> 1) & 3)) << 3));
    }
  };
  auto RDB = [&](const f16* buf, half8 (&bv)[3]) {
#pragma unroll
    for (int j = 0; j < 3; ++j) {
      const int r = wn * 48 + j * 16 + c;
      bv[j] = *(const half8*)(buf + 8192 + r * 32 + ((g16 ^ ((r >> 1) & 3)) << 3));
    }
  };

  // prologue
  SA(0, smem); SB(0, smem);
  VMCNT0;
  BAR;

#pragma unroll 1
  for (int t = 0; t < NT; ++t) {
    f16* bufR = smem + (t & 1) * 14336;
    f16* bufW = smem + ((t & 1) ^ 1) * 14336;
    const bool st = (t + 1) < NT;
    half8 av[4], bv[3];

    RDA(bufR, 0, av); RDB(bufR, bv);
    if (st) SA(t + 1, bufW);
    __builtin_amdgcn_s_setprio(1);
#pragma unroll
    for (int i = 0; i < 4; ++i)
#pragma unroll
      for (int j = 0; j < 3; ++j)
        acc[i][j] = __builtin_amdgcn_mfma_f32_16x16x32_f16(av[i], bv[j], acc[i][j], 0, 0, 0);
    __builtin_amdgcn_s_setprio(0);
    RDA(bufR, 1, av);
    if (st) SB(t + 1, bufW);
    __builtin_amdgcn_s_setprio(1);
#pragma unroll
    for (int i = 0; i < 4; ++i)
#pragma unroll
      for (int j = 0; j < 3; ++j)
        acc[4 + i][j] = __builtin_amdgcn_mfma_f32_16x16x32_f16(av[i], bv[j], acc[4 + i][j], 0, 0, 0);
    __builtin_amdgcn_s_setprio(0);
    VMCNT0;
    BAR;
  }
}

// ---------------- QKV GEMM (writes Q,K normal; V transposed) ----------------
__global__ __launch_bounds__(512, 2) void k_gemm_qkv8(const f16* __restrict__ X16, const f16* __restrict__ WT,
    const float* __restrict__ bq, const float* __restrict__ bk, const float* __restrict__ bv,
    f16* __restrict__ Qo, f16* __restrict__ Ko, f16* __restrict__ VT)
{
  __shared__ f16 smem[28672];            // 56 KiB
  f32x4 acc[8][3];
  const int lin = blockIdx.x;
  const int xcd = lin & 7, chunk = lin >> 3;      // [0,96)
  const int bx = xcd * 8 + chunk / 12;            // [0,64)
  const int by = chunk % 12;                      // [0,12)
  const int brow0 = bx * 256;
  const int t = threadIdx.x, w = t >> 6, lane = t & 63;
  gemm256c(X16 + (size_t)brow0 * 768, WT + (size_t)by * 192 * 768, smem, acc, w, lane);

  const int wm = w >> 2, wn = w & 3;
  const int c = lane & 15, g16 = lane >> 4;
  const int which = by >> 2;             // 0:q 1:k 2:v
  const int colhdr = (by & 3) * 192;
  const float* bias = which == 0 ? bq : (which == 1 ? bk : bv);
  float bb[3];
#pragma unroll
  for (int j = 0; j < 3; ++j) bb[j] = bias[colhdr + wn * 48 + j * 16 + c];

  f16* ep = smem;
  if (which < 2) {
    f16* QK = which == 0 ? Qo : Ko;
#pragma unroll 1
    for (int p = 0; p < 2; ++p) {
      __syncthreads();
      if (wm == p) {
#pragma unroll
        for (int ii = 0; ii < 8; ++ii)
#pragma unroll
          for (int j = 0; j < 3; ++j)
#pragma unroll
            for (int r = 0; r < 4; ++r)
              ep[((ii >> 2) * 64 + (ii & 3) * 16 + g16 * 4 + r) * 200 + wn * 48 + j * 16 + c]
                  = (f16)(acc[ii][j][r] + bb[j]);
      }
      __syncthreads();
      const int row = t >> 2, sg = (t & 3) * 48;
      f16* dst = QK + (size_t)(brow0 + p * 128 + row) * 768 + colhdr + sg;
      const f16* sp = ep + row * 200 + sg;
#pragma unroll
      for (int u = 0; u < 6; ++u) *(half8*)(dst + u * 8) = *(const half8*)(sp + u * 8);
    }
  } else {
    const int bIdx = brow0 >> 12;
#pragma unroll 1
    for (int p = 0; p < 2; ++p) {
      __syncthreads();
      if (wm == p) {
#pragma unroll
        for (int ii = 0; ii < 8; ++ii)
#pragma unroll
          for (int j = 0; j < 3; ++j)
#pragma unroll
            for (int r = 0; r < 4; ++r)
              ep[(wn * 48 + j * 16 + c) * 136 + (ii >> 2) * 64 + (ii & 3) * 16 + g16 * 4 + r]
                  = (f16)(acc[ii][j][r] + bb[j]);
      }
      __syncthreads();
      if (t < 384) {
        const int cl = t >> 1, sg = (t & 1) * 64;
        const int vcol = colhdr + cl;
        const int h = vcol >> 6, d = vcol & 63;
        f16* dst = VT + ((size_t)(bIdx * 12 + h) * 64 + d) * 4096 + (brow0 & 4095) + p * 128 + sg;
        const f16* sp = ep + cl * 136 + sg;
#pragma unroll
        for (int u = 0; u < 8; ++u) *(half8*)(dst + u * 8) = *(const half8*)(sp + u * 8);
      }
    }
  }
}

// ---------------- final GEMM ----------------
__global__ __launch_bounds__(512, 2) void k_gemm_out8(const f16* __restrict__ ATT, const f16* __restrict__ WOT,
    const float* __restrict__ bo, float* __restrict__ out)
{
  __shared__ f16 smem[28672];
  f32x4 acc[8][3];
  const int lin = blockIdx.x;
  const int xcd = lin & 7, chunk = lin >> 3;      // [0,32)
  const int bx = xcd * 8 + (chunk >> 2);          // [0,64)
  const int by = chunk & 3;                       // [0,4)
  const int brow0 = bx * 256;
  const int t = threadIdx.x, w = t >> 6, lane = t & 63;
  gemm256c(ATT + (size_t)brow0 * 768, WOT + (size_t)by * 192 * 768, smem, acc, w, lane);

  const int wm = w >> 2, wn = w & 3;
  const int c = lane & 15, g16 = lane >> 4;
  float bb[3];
#pragma unroll
  for (int j = 0; j < 3; ++j) bb[j] = bo[by * 192 + wn * 48 + j * 16 + c];
#pragma unroll
  for (int ii = 0; ii < 8; ++ii) {
    const int row0 = brow0 + wm * 128 + (ii >> 2) * 64 + (ii & 3) * 16 + g16 * 4;
#pragma unroll
    for (int j = 0; j < 3; ++j) {
      const int col = by * 192 + wn * 48 + j * 16 + c;
#pragma unroll
      for (int r = 0; r < 4; ++r)
        out[(size_t)(row0 + r) * 768 + col] = acc[ii][j][r] + bb[j];
    }
  }
}

// =====================================================================
// 128-tile GEMM core (kept for kvs)
// =====================================================================
template<int BN>
DEVINL void gemm_tile(const f16* A, int lda, const f16* Bt, int ldb, int K,
                      f16* As, f16* Bs, f32x4 (&acc)[4][BN/32])
{
  constexpr int NF = BN/32;
  const int t = threadIdx.x;
  const int w = t >> 6, lane = t & 63;
  const int g = lane >> 4, c = lane & 15;
  const int wr = w >> 1, wc = w & 1;
  const int srow = lane >> 2;
  const int sseg = (lane & 3) * 8;

#pragma unroll
  for (int i = 0; i < 4; ++i)
#pragma unroll
    for (int j = 0; j < NF; ++j)
      acc[i][j] = f32x4{0.f, 0.f, 0.f, 0.f};

  for (int k0 = 0; k0 < K; k0 += 32) {
#pragma unroll
    for (int r = 0; r < 2; ++r) {
      const int rowblk = (w + 4*r) * 16;
      gload_lds16(A + (size_t)(rowblk + srow) * lda + k0 + sseg, As + rowblk*32);
    }
#pragma unroll
    for (int r = 0; r < BN/64; ++r) {
      const int rowblk = (w + 4*r) * 16;
      gload_lds16(Bt + (size_t)(rowblk + srow) * ldb + k0 + sseg, Bs + rowblk*32);
    }
    __syncthreads();
    half8 av[4], bv[NF];
#pragma unroll
    for (int i = 0; i < 4; ++i)
      av[i] = *(const half8*)(As + (wr*64 + i*16 + c)*32 + g*8);
#pragma unroll
    for (int j = 0; j < NF; ++j)
      bv[j] = *(const half8*)(Bs + (wc*(BN/2) + j*16 + c)*32 + g*8);
#pragma unroll
    for (int i = 0; i < 4; ++i)
#pragma unroll
      for (int j = 0; j < NF; ++j)
        acc[i][j] = __builtin_amdgcn_mfma_f32_16x16x32_f16(av[i], bv[j], acc[i][j], 0, 0, 0);
    __syncthreads();
  }
}

// ---------------- prep: x cast + proj cast + 4x W transpose ----------------
__global__ __launch_bounds__(256) void k_prep(const float* __restrict__ X, f16* __restrict__ X16,
    const float* __restrict__ P, f16* __restrict__ PF,
    const float* __restrict__ Wq, const float* __restrict__ Wk,
    const float* __restrict__ Wv, const float* __restrict__ Wo,
    f16* __restrict__ WQKVT, f16* __restrict__ WOT)
{
  __shared__ float ls[64][65];
  const int t = threadIdx.x;
  if (blockIdx.x < 12288) {
    const size_t i = ((size_t)blockIdx.x*256 + t) * 4;
    const float4 v = *(const float4*)(X + i);
    half4 h;
    h[0] = (f16)v.x; h[1] = (f16)v.y; h[2] = (f16)v.z; h[3] = (f16)v.w;
    *(half4*)(X16 + i) = h;
    if (blockIdx.x == 0)
      for (int i2 = t; i2 < 8192; i2 += 256) PF[i2] = (f16)(NORMALIZER * P[i2]);
    return;
  }
  const int zz = blockIdx.x - 12288;     // [0,576)
  const int z = zz / 144, rem = zz - z*144;
  const int k0 = (rem / 12) * 64, n0 = (rem % 12) * 64;
  const float* W = z == 0 ? Wq : (z == 1 ? Wk : (z == 2 ? Wv : Wo));
  f16* Wt = z < 3 ? (WQKVT + (size_t)z*768*768) : WOT;
#pragma unroll
  for (int it = 0; it < 4; ++it) {
    const int r = it*16 + (t >> 4);
    const int cs = (t & 15) * 4;
    const float4 v = *(const float4*)(W + (size_t)(k0 + r)*768 + n0 + cs);
    ls[r][cs+0] = v.x; ls[r][cs+1] = v.y; ls[r][cs+2] = v.z; ls[r][cs+3] = v.w;
  }
  __syncthreads();
  const int n = t >> 2;
  const int seg = (t & 3) * 16;
  half8 ov[2];
#pragma unroll
  for (int i = 0; i < 16; ++i) ov[i>>3][i&7] = (f16)ls[seg + i][n];
  f16* dst = Wt + (size_t)(n0 + n)*768 + k0 + seg;
  *(half8*)dst = ov[0];
  *(half8*)(dst + 8) = ov[1];
}

// ---------------- feature kernels ----------------
DEVINL void feat_common(const f16* base, const f16* PROJF,
                        f16* qs, f16* ps, float* dd, float* diag_s)
{
  const int t = threadIdx.x, w = t >> 6, lane = t & 63;
#pragma unroll
  for (int it = 0; it < 2; ++it) {
    const int rowblk = it*32 + w*8;
    gload_lds16(base + (size_t)(rowblk + (lane>>3))*768 + (lane&7)*8, qs + rowblk*64);
  }
#pragma unroll
  for (int it = 0; it < 4; ++it) {
    const int rowblk = it*32 + w*8;
    gload_lds16(PROJF + (size_t)(rowblk + (lane>>3))*64 + (lane&7)*8, ps + rowblk*64);
  }
  __syncthreads();
  {
    // diag: all 256 lanes (4 lanes per row, 16 elems each, shfl-combine)
    const int row = t >> 2, q = t & 3;
    const f16* kr = qs + row*64 + q*16;
    half8 v0 = *(const half8*)(kr);
    half8 v1 = *(const half8*)(kr + 8);
    float s = 0.f;
#pragma unroll
    for (int d2 = 0; d2 < 8; ++d2) { float a = (float)v0[d2]; s += a*a; }
#pragma unroll
    for (int d2 = 0; d2 < 8; ++d2) { float a = (float)v1[d2]; s += a*a; }
    s += __shfl_xor(s, 1);
    s += __shfl_xor(s, 2);
    if (q == 0) diag_s[row] = 0.0625f * s;
  }
  const int g = lane >> 4, c = lane & 15;
  const int wr = w >> 1, wc = w & 1;
  f32x4 facc[2][4];
#pragma unroll
  for (int i = 0; i < 2; ++i)
#pragma unroll
    for (int j = 0; j < 4; ++j) facc[i][j] = f32x4{0.f,0.f,0.f,0.f};
#pragma unroll
  for (int kk = 0; kk < 2; ++kk) {
    half8 av[2], bv[4];
#pragma unroll
    for (int i = 0; i < 2; ++i) av[i] = *(const half8*)(qs + (wr*32 + i*16 + c)*64 + kk*32 + g*8);
#pragma unroll
    for (int j = 0; j < 4; ++j) bv[j] = *(const half8*)(ps + (wc*64 + j*16 + c)*64 + kk*32 + g*8);
#pragma unroll
    for (int i = 0; i < 2; ++i)
#pragma unroll
      for (int j = 0; j < 4; ++j)
        facc[i][j] = __builtin_amdgcn_mfma_f32_16x16x32_f16(av[i], bv[j], facc[i][j], 0, 0, 0);
  }
#pragma unroll
  for (int i = 0; i < 2; ++i)
#pragma unroll
    for (int j = 0; j < 4; ++j)
#pragma unroll
      for (int r = 0; r < 4; ++r)
        dd[(wr*32 + i*16 + g*4 + r)*129 + wc*64 + j*16 + c] = facc[i][j][r];
  __syncthreads();
}

__global__ __launch_bounds__(256) void k_kfeat(const f16* __restrict__ Kin, const f16* __restrict__ PROJF,
    f16* __restrict__ KPT, float* __restrict__ KSP)
{
  __shared__ f16 qs[64*64];
  __shared__ f16 ps[128*64];
  __shared__ float dd[64*129];
  __shared__ float diag_s[64];
  const int t = threadIdx.x;
  const int lb = blockIdx.x, bh = blockIdx.y;
  const int b = bh / 12, h = bh - b*12;
  feat_common(Kin + ((size_t)(b*4096 + lb*64))*768 + h*64, PROJF, qs, ps, dd, diag_s);
  const int l = t >> 2, s = t & 3;
  float v[32];
#pragma unroll
  for (int j = 0; j < 32; ++j) v[j] = dd[l*129 + s*32 + j];
  float mx = v[0];
#pragma unroll
  for (int j = 1; j < 32; ++j) mx = fmaxf(mx, v[j]);
  mx = fmaxf(mx, __shfl_xor(mx, 1));
  mx = fmaxf(mx, __shfl_xor(mx, 2));
  const float off = diag_s[l] + mx;
#pragma unroll
  for (int j = 0; j < 32; ++j) dd[l*129 + s*32 + j] = RATIO * (__expf(v[j] - off) + FEPS);
  __syncthreads();
  {
    const int m = t >> 1, hf = t & 1;
    float sm = 0.f;
#pragma unroll 8
    for (int l2 = hf*32; l2 < hf*32 + 32; ++l2) sm += dd[l2*129 + m];
    sm += __shfl_xor(sm, 1);
    if (hf == 0) KSP[((size_t)bh*64 + lb)*128 + m] = sm;
  }
  const int m = t >> 1, hf = t & 1;
  half8 ov[4];
#pragma unroll
  for (int i2 = 0; i2 < 32; ++i2) ov[i2>>3][i2&7] = (f16)dd[(hf*32 + i2)*129 + m];
  f16* dst = KPT + ((size_t)bh*128 + m)*4096 + lb*64 + hf*32;
#pragma unroll
  for (int q8 = 0; q8 < 4; ++q8) *(half8*)(dst + q8*8) = ov[q8];
}

// ---------------- kvs: [48] (128m x 64d) = k'^T @ v, chunked over L ----------------
__global__ __launch_bounds__(256) void k_kvs(const f16* __restrict__ KPT, const f16* __restrict__ VT,
    float* __restrict__ KVSP)
{
  __shared__ f16 As[128*32], Bs[64*32];
  f32x4 acc[4][2];
  const int chunk = blockIdx.x, bh = blockIdx.y;   // (8, 48)
  gemm_tile<64>(KPT + (size_t)bh*128*4096 + chunk*512, 4096,
                VT  + (size_t)bh*64*4096  + chunk*512, 4096, 512, As, Bs, acc);
  const int t = threadIdx.x, w = t>>6, lane = t&63, g = lane>>4, c = lane&15;
  const int wr = w>>1, wc = w&1;
  float* dst = KVSP + (size_t)(chunk*48 + bh)*128*64;
#pragma unroll
  for (int i = 0; i < 4; ++i) {
    const int row0 = wr*64 + i*16 + g*4;
#pragma unroll
    for (int j = 0; j < 2; ++j) {
      const int col = wc*32 + j*16 + c;
#pragma unroll
      for (int r = 0; r < 4; ++r) dst[(size_t)(row0 + r)*64 + col] = acc[i][j][r];
    }
  }
}

__global__ __launch_bounds__(256) void k_reduce(const float* __restrict__ KVSP, const float* __restrict__ KSP,
    f16* __restrict__ KVST, float* __restrict__ KS)
{
  const int i = blockIdx.x*256 + threadIdx.x;
  if (i < 48*128*64) {
    const int bh = i >> 13, md = i & 8191, m = md >> 6, d = md & 63;
    float s = 0.f;
#pragma unroll
    for (int c = 0; c < 8; ++c) s += KVSP[((size_t)(c*48 + bh)*128 + m)*64 + d];
    KVST[((size_t)bh*64 + d)*128 + m] = (f16)s;
  }
  if (i < 48*128) {
    const int bh = i >> 7, m = i & 127;
    float s = 0.f;
#pragma unroll 8
    for (int lb = 0; lb < 64; ++lb) s += KSP[((size_t)bh*64 + lb)*128 + m];
    KS[i] = s;
  }
}

// ---------------- fused q-feature + num GEMM + normalize -> ATT ----------------
__global__ __launch_bounds__(256) void k_qfn(const f16* __restrict__ Q, const f16* __restrict__ PROJF,
    const float* __restrict__ KS, const f16* __restrict__ KVST, f16* __restrict__ ATT)
{
  __shared__ f16 qs[64*64];
  __shared__ f16 ps[128*64];
  __shared__ float dd[64*129];
  __shared__ float diag_s[64];
  __shared__ float den_s[64];
  __shared__ f16 qp[64*128];
  __shared__ float ks_s[128];
  const int t = threadIdx.x;
  const int lb = blockIdx.x, bh = blockIdx.y;
  const int b = bh / 12, h = bh - b*12;
  if (t < 128) ks_s[t] = KS[bh*128 + t];
  feat_common(Q + ((size_t)(b*4096 + lb*64))*768 + h*64, PROJF, qs, ps, dd, diag_s);

  const int w = t >> 6, lane = t & 63, g16 = lane >> 4, c = lane & 15;
  const int wr = w >> 1, wc = w & 1;
  half8 bv2[2][4];
#pragma unroll
  for (int j = 0; j < 2; ++j) {
    const int d = wc*32 + j*16 + c;
#pragma unroll
    for (int kk = 0; kk < 4; ++kk)
      bv2[j][kk] = *(const half8*)(KVST + (size_t)bh*8192 + d*128 + kk*32 + g16*8);
  }

  const int l = t >> 2, s = t & 3;
  float v[32];
#pragma unroll
  for (int j = 0; j < 32; ++j) v[j] = dd[l*129 + s*32 + j];
  float mx = v[0];
#pragma unroll
  for (int j = 1; j < 32; ++j) mx = fmaxf(mx, v[j]);
  mx = fmaxf(mx, __shfl_xor(mx, 1));
  mx = fmaxf(mx, __shfl_xor(mx, 2));
  const float off = diag_s[l] + mx;
  half8 ov[4];
  float dp = 0.f;
#pragma unroll
  for (int j = 0; j < 32; ++j) {
    const float e = RATIO * (__expf(v[j] - off) + FEPS);
    ov[j>>3][j&7] = (f16)e;
    dp += e * ks_s[s*32 + j];
  }
  dp += __shfl_xor(dp, 1);
  dp += __shfl_xor(dp, 2);
  if (s == 0) den_s[l] = dp;
#pragma unroll
  for (int k = 0; k < 4; ++k)
    *(half8*)(qp + l*128 + (((4*s + k) ^ (l & 7)) << 3)) = ov[k];
  __syncthreads();

  f32x4 acc2[2][2];
#pragma unroll
  for (int i = 0; i < 2; ++i)
#pragma unroll
    for (int j = 0; j < 2; ++j) acc2[i][j] = f32x4{0.f,0.f,0.f,0.f};
#pragma unroll
  for (int kk = 0; kk < 4; ++kk) {
    half8 av2[2];
#pragma unroll
    for (int i = 0; i < 2; ++i) {
      const int l2 = wr*32 + i*16 + c;
      av2[i] = *(const half8*)(qp + l2*128 + (((kk*4 + g16) ^ (l2 & 7)) << 3));
    }
#pragma unroll
    for (int i = 0; i < 2; ++i)
#pragma unroll
      for (int j = 0; j < 2; ++j)
        acc2[i][j] = __builtin_amdgcn_mfma_f32_16x16x32_f16(av2[i], bv2[j][kk], acc2[i][j], 0, 0, 0);
  }

  f16* ep = ps;   // [64][72]
#pragma unroll
  for (int i = 0; i < 2; ++i)
#pragma unroll
    for (int j = 0; j < 2; ++j)
#pragma unroll
      for (int r = 0; r < 4; ++r) {
        const int l3 = wr*32 + i*16 + g16*4 + r;
        ep[l3*72 + wc*32 + j*16 + c] = (f16)(acc2[i][j][r] / den_s[l3]);
      }
  __syncthreads();
  const int row = t >> 2, sg = (t & 3) * 16;
  f16* dst = ATT + ((size_t)bh*4096 + lb*64 + row)*64 + sg;
  const f16* sp = ep + row*72 + sg;
  *(half8*)dst = *(const half8*)sp;
  *(half8*)(dst + 8) = *(const half8*)(sp + 8);
}

// ---------------- launcher ----------------
extern "C" void kernel_launch(void* const* d_in, const int* in_sizes, int n_in,
                              void* d_out, int out_size, void* d_ws, size_t ws_size,
                              hipStream_t stream)
{
  const float* x    = (const float*)d_in[0];
  const float* Wq   = (const float*)d_in[1];
  const float* bq   = (const float*)d_in[2];
  const float* Wk   = (const float*)d_in[3];
  const float* bk   = (const float*)d_in[4];
  const float* Wv   = (const float*)d_in[5];
  const float* bv   = (const float*)d_in[6];
  const float* Wo   = (const float*)d_in[7];
  const float* bo   = (const float*)d_in[8];
  const float* proj = (const float*)d_in[9];
  float* out = (float*)d_out;
  char* ws = (char*)d_ws;

  f16*   WQKVT = (f16*)(ws + OFF_WQKVT);
  f16*   WOT   = (f16*)(ws + OFF_WOT);
  f16*   PROJF = (f16*)(ws + OFF_PROJF);
  float* KS    = (float*)(ws + OFF_KS);
  float* KSP   = (float*)(ws + OFF_KSP);
  f16*   KVST  = (f16*)(ws + OFF_KVST);
  float* KVSP  = (float*)(ws + OFF_KVSP);
  f16*   X16   = (f16*)(ws + OFF_X16);
  f16*   ATT   = (f16*)(ws + OFF_ATT);
  f16*   Q16   = (f16*)(ws + OFF_Q16);
  f16*   K16   = (f16*)(ws + OFF_K16);
  f16*   VT    = (f16*)(ws + OFF_VT);
  f16*   KPT   = (f16*)(ws + OFF_KPT);

  k_prep<<<12864, 256, 0, stream>>>(x, X16, proj, PROJF, Wq, Wk, Wv, Wo, WQKVT, WOT);
  k_gemm_qkv8<<<768, 512, 0, stream>>>(X16, WQKVT, bq, bk, bv, Q16, K16, VT);
  k_kfeat<<<dim3(64,48), 256, 0, stream>>>(K16, PROJF, KPT, KSP);
  k_kvs<<<dim3(8,48), 256, 0, stream>>>(KPT, VT, KVSP);
  k_reduce<<<1536, 256, 0, stream>>>(KVSP, KSP, KVST, KS);
  k_qfn<<<dim3(64,48), 256, 0, stream>>>(Q16, PROJF, KS, KVST, ATT);
  k_gemm_out8<<<256, 512, 0, stream>>>(ATT, WOT, bo, out);
}

// Round 11
// 243.549 us; speedup vs baseline: 1.4052x; 1.0107x over previous
//
#include <hip/hip_runtime.h>

typedef _Float16 f16;
typedef __attribute__((ext_vector_type(8))) _Float16 half8;
typedef __attribute__((ext_vector_type(4))) _Float16 half4;
typedef __attribute__((ext_vector_type(4))) float f32x4;

#define DEVINL static __device__ __forceinline__

constexpr float NORMALIZER = 0.35355339059327373f;  // 64^-0.25
constexpr float RATIO      = 0.08838834764831845f;  // 1/sqrt(128)
constexpr float FEPS       = 1e-6f;

// ---------------- workspace layout (bytes) ----------------
constexpr size_t OFF_WQKVT = 0;                                   // [2304][768] f16
constexpr size_t OFF_WOT   = OFF_WQKVT + (size_t)2304*768*2;      // [768][768] f16
constexpr size_t OFF_PROJF = OFF_WOT   + (size_t)768*768*2;       // [128][64] f16 (pre-scaled)
constexpr size_t OFF_KS    = OFF_PROJF + (size_t)128*64*2;        // [48][128] f32
constexpr size_t OFF_KSP   = OFF_KS    + (size_t)48*128*4;        // [48*64][128] f32
constexpr size_t OFF_KVST  = OFF_KSP   + (size_t)48*64*128*4;     // [48][64][128] f16
constexpr size_t OFF_KVSP  = OFF_KVST  + (size_t)48*64*128*2;     // [8][48][128][64] f32
constexpr size_t OFF_X16   = OFF_KVSP  + (size_t)8*48*128*64*4;   // [16384][768] f16
constexpr size_t OFF_ATT   = OFF_X16;                              // alias (x16 dead after QKV GEMM)
constexpr size_t OFF_Q16   = OFF_X16 + (size_t)16384*768*2;
constexpr size_t OFF_K16   = OFF_Q16 + (size_t)16384*768*2;
constexpr size_t OFF_VT    = OFF_K16 + (size_t)16384*768*2;       // [48][64][4096] f16
constexpr size_t OFF_KPT   = OFF_VT  + (size_t)16384*768*2;       // [48][128][4096] f16

// ---------------- helpers ----------------
DEVINL void gload_lds16(const f16* g, f16* lds) {
  __builtin_amdgcn_global_load_lds(
      (const __attribute__((address_space(1))) void*)g,
      (__attribute__((address_space(3))) void*)lds, 16, 0, 0);
}

#define VMCNT0    asm volatile("s_waitcnt vmcnt(0)" ::: "memory")
#define BAR       __builtin_amdgcn_s_barrier()

// =====================================================================
// NEW QKV core: 256x128 tile, BK=32, 4 waves (2M x 2N), wave tile 128x64.
// reads/MFMA = (8+4)/32 = 0.375 (vs 0.458 at 128x48) -> -18% LDS-pipe
// traffic (the measured binder); MFMA density/wave 24->32 per tile.
// LDS: A[256][32] 16KB + B[128][32] 8KB = 24KB/buf; dbuf 48KB -> 2 blk/CU.
// acc[8][4] = 128 AGPR + ~70 VGPR < 256 cap at (256,2): no spill.
// Swizzle (both sides): 16B-seg' = seg ^ ((r>>1)&3).
// =====================================================================
DEVINL void gemm256n(const f16* __restrict__ Ag, const f16* __restrict__ Bg,
                     f16* smem, f32x4 (&acc)[8][4], int w, int lane)
{
  constexpr int NT = 24;                 // 768 / 32
  const int wm = w >> 1, wn = w & 1;
  const int c = lane & 15, g16 = lane >> 4;
  const int tid = threadIdx.x;

#pragma unroll
  for (int i = 0; i < 8; ++i)
#pragma unroll
    for (int j = 0; j < 4; ++j)
      acc[i][j] = f32x4{0.f, 0.f, 0.f, 0.f};

  auto SA = [&](int tt, f16* buf) {      // A[256][32]: 1024 segs, 4/thread
#pragma unroll
    for (int u = 0; u < 4; ++u) {
      const int id = u * 256 + tid;
      const int r = id >> 2, sg = id & 3;
      const int seg = sg ^ ((r >> 1) & 3);
      gload_lds16(Ag + (size_t)r * 768 + tt * 32 + seg * 8, buf + (u * 256 + w * 64) * 8);
    }
  };
  auto SB = [&](int tt, f16* buf) {      // B[128][32]: 512 segs, 2/thread
#pragma unroll
    for (int u = 0; u < 2; ++u) {
      const int id = u * 256 + tid;
      const int r = id >> 2, sg = id & 3;
      const int seg = sg ^ ((r >> 1) & 3);
      gload_lds16(Bg + (size_t)r * 768 + tt * 32 + seg * 8, buf + 8192 + (u * 256 + w * 64) * 8);
    }
  };
  auto RDA = [&](const f16* buf, int mh, half8 (&av)[4]) {
#pragma unroll
    for (int i = 0; i < 4; ++i) {
      const int r = wm * 128 + mh * 64 + i * 16 + c;
      av[i] = *(const half8*)(buf + r * 32 + ((g16 ^ ((r >> 1) & 3)) << 3));
    }
  };
  auto RDB = [&](const f16* buf, half8 (&bv)[4]) {
#pragma unroll
    for (int j = 0; j < 4; ++j) {
      const int r = wn * 64 + j * 16 + c;
      bv[j] = *(const half8*)(buf + 8192 + r * 32 + ((g16 ^ ((r >> 1) & 3)) << 3));
    }
  };

  // prologue
  SA(0, smem); SB(0, smem);
  VMCNT0;
  BAR;

#pragma unroll 1
  for (int t = 0; t < NT; ++t) {
    f16* bufR = smem + (t & 1) * 12288;
    f16* bufW = smem + ((t & 1) ^ 1) * 12288;
    const bool st = (t + 1) < NT;
    half8 av[4], bv[4];

    RDB(bufR, bv); RDA(bufR, 0, av);
    if (st) SA(t + 1, bufW);
    __builtin_amdgcn_s_setprio(1);
#pragma unroll
    for (int i = 0; i < 4; ++i)
#pragma unroll
      for (int j = 0; j < 4; ++j)
        acc[i][j] = __builtin_amdgcn_mfma_f32_16x16x32_f16(av[i], bv[j], acc[i][j], 0, 0, 0);
    __builtin_amdgcn_s_setprio(0);
    RDA(bufR, 1, av);
    if (st) SB(t + 1, bufW);
    __builtin_amdgcn_s_setprio(1);
#pragma unroll
    for (int i = 0; i < 4; ++i)
#pragma unroll
      for (int j = 0; j < 4; ++j)
        acc[4 + i][j] = __builtin_amdgcn_mfma_f32_16x16x32_f16(av[i], bv[j], acc[4 + i][j], 0, 0, 0);
    __builtin_amdgcn_s_setprio(0);
    VMCNT0;
    BAR;
  }
}

// ---------------- QKV GEMM (new core; writes Q,K normal; V transposed) ----------------
__global__ __launch_bounds__(256, 2) void k_gemm_qkv9(const f16* __restrict__ X16, const f16* __restrict__ WT,
    const float* __restrict__ bq, const float* __restrict__ bk, const float* __restrict__ bv,
    f16* __restrict__ Qo, f16* __restrict__ Ko, f16* __restrict__ VT)
{
  __shared__ f16 smem[24576];            // 48 KiB
  f32x4 acc[8][4];
  // 1152 blocks = 8 xcd * 144; per XCD: 8 bx x 18 by
  const int lin = blockIdx.x;
  const int xcd = lin & 7, chunk = lin >> 3;      // [0,144)
  const int bx = xcd * 8 + chunk / 18;            // [0,64)
  const int by = chunk % 18;                      // [0,18)
  const int brow0 = bx * 256;
  const int t = threadIdx.x, w = t >> 6, lane = t & 63;
  gemm256n(X16 + (size_t)brow0 * 768, WT + (size_t)by * 128 * 768, smem, acc, w, lane);

  const int wm = w >> 1, wn = w & 1;
  const int c = lane & 15, g16 = lane >> 4;
  const int which = by / 6;              // 0:q 1:k 2:v
  const int colhdr = (by % 6) * 128;
  const float* bias = which == 0 ? bq : (which == 1 ? bk : bv);
  float bb[4];
#pragma unroll
  for (int j = 0; j < 4; ++j) bb[j] = bias[colhdr + wn * 64 + j * 16 + c];

  f16* ep = smem;
  if (which < 2) {
    // ---- Q/K: row-major bounce [128][136], two row-half passes ----
    f16* QK = which == 0 ? Qo : Ko;
#pragma unroll 1
    for (int p = 0; p < 2; ++p) {
      __syncthreads();
      if (wm == p) {
#pragma unroll
        for (int ii = 0; ii < 8; ++ii)
#pragma unroll
          for (int j = 0; j < 4; ++j)
#pragma unroll
            for (int r = 0; r < 4; ++r)
              ep[(ii * 16 + g16 * 4 + r) * 136 + wn * 64 + j * 16 + c]
                  = (f16)(acc[ii][j][r] + bb[j]);
      }
      __syncthreads();
      const int row = t >> 1, sg = (t & 1) * 64;
      f16* dst = QK + (size_t)(brow0 + p * 128 + row) * 768 + colhdr + sg;
      const f16* sp = ep + row * 136 + sg;
#pragma unroll
      for (int u = 0; u < 8; ++u) *(half8*)(dst + u * 8) = *(const half8*)(sp + u * 8);
    }
  } else {
    // ---- V: transposed bounce [128 col][136], two row-half passes ----
    const int bIdx = brow0 >> 12;
#pragma unroll 1
    for (int p = 0; p < 2; ++p) {
      __syncthreads();
      if (wm == p) {
#pragma unroll
        for (int ii = 0; ii < 8; ++ii)
#pragma unroll
          for (int j = 0; j < 4; ++j)
#pragma unroll
            for (int r = 0; r < 4; ++r)
              ep[(wn * 64 + j * 16 + c) * 136 + ii * 16 + g16 * 4 + r]
                  = (f16)(acc[ii][j][r] + bb[j]);
      }
      __syncthreads();
      const int cl = t >> 1, sg = (t & 1) * 64;
      const int vcol = colhdr + cl;
      const int h = vcol >> 6, d = vcol & 63;
      f16* dst = VT + ((size_t)(bIdx * 12 + h) * 64 + d) * 4096 + (brow0 & 4095) + p * 128 + sg;
      const f16* sp = ep + cl * 136 + sg;
#pragma unroll
      for (int u = 0; u < 8; ++u) *(half8*)(dst + u * 8) = *(const half8*)(sp + u * 8);
    }
  }
}

// =====================================================================
// OLD 512-thread 256x192 core (kept, proven, for the output GEMM)
// =====================================================================
DEVINL void gemm256c(const f16* __restrict__ Ag, const f16* __restrict__ Bg,
                     f16* smem, f32x4 (&acc)[8][3], int w, int lane)
{
  constexpr int NT = 24;                 // 768 / 32
  const int wm = w >> 2, wn = w & 3;
  const int c = lane & 15, g16 = lane >> 4;
  const int tid = threadIdx.x;

#pragma unroll
  for (int i = 0; i < 8; ++i)
#pragma unroll
    for (int j = 0; j < 3; ++j)
      acc[i][j] = f32x4{0.f, 0.f, 0.f, 0.f};

  auto SA = [&](int tt, f16* buf) {
#pragma unroll
    for (int u = 0; u < 2; ++u) {
      const int id = u * 512 + tid;
      const int r = id >> 2, sg = id & 3;
      const int seg = sg ^ ((r >> 1) & 3);
      gload_lds16(Ag + (size_t)r * 768 + tt * 32 + seg * 8, buf + (u * 512 + w * 64) * 8);
    }
  };
  auto SB = [&](int tt, f16* buf) {
    {
      const int r = tid >> 2, sg = tid & 3;
      const int seg = sg ^ ((r >> 1) & 3);
      gload_lds16(Bg + (size_t)r * 768 + tt * 32 + seg * 8, buf + 8192 + w * 64 * 8);
    }
    if (w < 4) {
      const int id = 512 + tid;
      const int r = id >> 2, sg = id & 3;
      const int seg = sg ^ ((r >> 1) & 3);
      gload_lds16(Bg + (size_t)r * 768 + tt * 32 + seg * 8, buf + 8192 + (512 + w * 64) * 8);
    }
  };
  auto RDA = [&](const f16* buf, int mh, half8 (&av)[4]) {
#pragma unroll
    for (int i = 0; i < 4; ++i) {
      const int r = wm * 128 + mh * 64 + i * 16 + c;
      av[i] = *(const half8*)(buf + r * 32 + ((g16 ^ ((r >> 1) & 3)) << 3));
    }
  };
  auto RDB = [&](const f16* buf, half8 (&bv)[3]) {
#pragma unroll
    for (int j = 0; j < 3; ++j) {
      const int r = wn * 48 + j * 16 + c;
      bv[j] = *(const half8*)(buf + 8192 + r * 32 + ((g16 ^ ((r >> 1) & 3)) << 3));
    }
  };

  SA(0, smem); SB(0, smem);
  VMCNT0;
  BAR;

#pragma unroll 1
  for (int t = 0; t < NT; ++t) {
    f16* bufR = smem + (t & 1) * 14336;
    f16* bufW = smem + ((t & 1) ^ 1) * 14336;
    const bool st = (t + 1) < NT;
    half8 av[4], bv[3];

    RDA(bufR, 0, av); RDB(bufR, bv);
    if (st) SA(t + 1, bufW);
    __builtin_amdgcn_s_setprio(1);
#pragma unroll
    for (int i = 0; i < 4; ++i)
#pragma unroll
      for (int j = 0; j < 3; ++j)
        acc[i][j] = __builtin_amdgcn_mfma_f32_16x16x32_f16(av[i], bv[j], acc[i][j], 0, 0, 0);
    __builtin_amdgcn_s_setprio(0);
    RDA(bufR, 1, av);
    if (st) SB(t + 1, bufW);
    __builtin_amdgcn_s_setprio(1);
#pragma unroll
    for (int i = 0; i < 4; ++i)
#pragma unroll
      for (int j = 0; j < 3; ++j)
        acc[4 + i][j] = __builtin_amdgcn_mfma_f32_16x16x32_f16(av[i], bv[j], acc[4 + i][j], 0, 0, 0);
    __builtin_amdgcn_s_setprio(0);
    VMCNT0;
    BAR;
  }
}

// ---------------- final GEMM (old core) ----------------
__global__ __launch_bounds__(512, 2) void k_gemm_out8(const f16* __restrict__ ATT, const f16* __restrict__ WOT,
    const float* __restrict__ bo, float* __restrict__ out)
{
  __shared__ f16 smem[28672];
  f32x4 acc[8][3];
  const int lin = blockIdx.x;
  const int xcd = lin & 7, chunk = lin >> 3;      // [0,32)
  const int bx = xcd * 8 + (chunk >> 2);          // [0,64)
  const int by = chunk & 3;                       // [0,4)
  const int brow0 = bx * 256;
  const int t = threadIdx.x, w = t >> 6, lane = t & 63;
  gemm256c(ATT + (size_t)brow0 * 768, WOT + (size_t)by * 192 * 768, smem, acc, w, lane);

  const int wm = w >> 2, wn = w & 3;
  const int c = lane & 15, g16 = lane >> 4;
  float bb[3];
#pragma unroll
  for (int j = 0; j < 3; ++j) bb[j] = bo[by * 192 + wn * 48 + j * 16 + c];
#pragma unroll
  for (int ii = 0; ii < 8; ++ii) {
    const int row0 = brow0 + wm * 128 + (ii >> 2) * 64 + (ii & 3) * 16 + g16 * 4;
#pragma unroll
    for (int j = 0; j < 3; ++j) {
      const int col = by * 192 + wn * 48 + j * 16 + c;
#pragma unroll
      for (int r = 0; r < 4; ++r)
        out[(size_t)(row0 + r) * 768 + col] = acc[ii][j][r] + bb[j];
    }
  }
}

// =====================================================================
// 128-tile GEMM core (kept for kvs)
// =====================================================================
template<int BN>
DEVINL void gemm_tile(const f16* A, int lda, const f16* Bt, int ldb, int K,
                      f16* As, f16* Bs, f32x4 (&acc)[4][BN/32])
{
  constexpr int NF = BN/32;
  const int t = threadIdx.x;
  const int w = t >> 6, lane = t & 63;
  const int g = lane >> 4, c = lane & 15;
  const int wr = w >> 1, wc = w & 1;
  const int srow = lane >> 2;
  const int sseg = (lane & 3) * 8;

#pragma unroll
  for (int i = 0; i < 4; ++i)
#pragma unroll
    for (int j = 0; j < NF; ++j)
      acc[i][j] = f32x4{0.f, 0.f, 0.f, 0.f};

  for (int k0 = 0; k0 < K; k0 += 32) {
#pragma unroll
    for (int r = 0; r < 2; ++r) {
      const int rowblk = (w + 4*r) * 16;
      gload_lds16(A + (size_t)(rowblk + srow) * lda + k0 + sseg, As + rowblk*32);
    }
#pragma unroll
    for (int r = 0; r < BN/64; ++r) {
      const int rowblk = (w + 4*r) * 16;
      gload_lds16(Bt + (size_t)(rowblk + srow) * ldb + k0 + sseg, Bs + rowblk*32);
    }
    __syncthreads();
    half8 av[4], bv[NF];
#pragma unroll
    for (int i = 0; i < 4; ++i)
      av[i] = *(const half8*)(As + (wr*64 + i*16 + c)*32 + g*8);
#pragma unroll
    for (int j = 0; j < NF; ++j)
      bv[j] = *(const half8*)(Bs + (wc*(BN/2) + j*16 + c)*32 + g*8);
#pragma unroll
    for (int i = 0; i < 4; ++i)
#pragma unroll
      for (int j = 0; j < NF; ++j)
        acc[i][j] = __builtin_amdgcn_mfma_f32_16x16x32_f16(av[i], bv[j], acc[i][j], 0, 0, 0);
    __syncthreads();
  }
}

// ---------------- prep: x cast + proj cast + 4x W transpose ----------------
__global__ __launch_bounds__(256) void k_prep(const float* __restrict__ X, f16* __restrict__ X16,
    const float* __restrict__ P, f16* __restrict__ PF,
    const float* __restrict__ Wq, const float* __restrict__ Wk,
    const float* __restrict__ Wv, const float* __restrict__ Wo,
    f16* __restrict__ WQKVT, f16* __restrict__ WOT)
{
  __shared__ float ls[64][65];
  const int t = threadIdx.x;
  if (blockIdx.x < 12288) {
    const size_t i = ((size_t)blockIdx.x*256 + t) * 4;
    const float4 v = *(const float4*)(X + i);
    half4 h;
    h[0] = (f16)v.x; h[1] = (f16)v.y; h[2] = (f16)v.z; h[3] = (f16)v.w;
    *(half4*)(X16 + i) = h;
    if (blockIdx.x == 0)
      for (int i2 = t; i2 < 8192; i2 += 256) PF[i2] = (f16)(NORMALIZER * P[i2]);
    return;
  }
  const int zz = blockIdx.x - 12288;     // [0,576)
  const int z = zz / 144, rem = zz - z*144;
  const int k0 = (rem / 12) * 64, n0 = (rem % 12) * 64;
  const float* W = z == 0 ? Wq : (z == 1 ? Wk : (z == 2 ? Wv : Wo));
  f16* Wt = z < 3 ? (WQKVT + (size_t)z*768*768) : WOT;
#pragma unroll
  for (int it = 0; it < 4; ++it) {
    const int r = it*16 + (t >> 4);
    const int cs = (t & 15) * 4;
    const float4 v = *(const float4*)(W + (size_t)(k0 + r)*768 + n0 + cs);
    ls[r][cs+0] = v.x; ls[r][cs+1] = v.y; ls[r][cs+2] = v.z; ls[r][cs+3] = v.w;
  }
  __syncthreads();
  const int n = t >> 2;
  const int seg = (t & 3) * 16;
  half8 ov[2];
#pragma unroll
  for (int i = 0; i < 16; ++i) ov[i>>3][i&7] = (f16)ls[seg + i][n];
  f16* dst = Wt + (size_t)(n0 + n)*768 + k0 + seg;
  *(half8*)dst = ov[0];
  *(half8*)(dst + 8) = ov[1];
}

// ---------------- feature kernels ----------------
DEVINL void feat_common(const f16* base, const f16* PROJF,
                        f16* qs, f16* ps, float* dd, float* diag_s)
{
  const int t = threadIdx.x, w = t >> 6, lane = t & 63;
#pragma unroll
  for (int it = 0; it < 2; ++it) {
    const int rowblk = it*32 + w*8;
    gload_lds16(base + (size_t)(rowblk + (lane>>3))*768 + (lane&7)*8, qs + rowblk*64);
  }
#pragma unroll
  for (int it = 0; it < 4; ++it) {
    const int rowblk = it*32 + w*8;
    gload_lds16(PROJF + (size_t)(rowblk + (lane>>3))*64 + (lane&7)*8, ps + rowblk*64);
  }
  __syncthreads();
  {
    const int row = t >> 2, q = t & 3;
    const f16* kr = qs + row*64 + q*16;
    half8 v0 = *(const half8*)(kr);
    half8 v1 = *(const half8*)(kr + 8);
    float s = 0.f;
#pragma unroll
    for (int d2 = 0; d2 < 8; ++d2) { float a = (float)v0[d2]; s += a*a; }
#pragma unroll
    for (int d2 = 0; d2 < 8; ++d2) { float a = (float)v1[d2]; s += a*a; }
    s += __shfl_xor(s, 1);
    s += __shfl_xor(s, 2);
    if (q == 0) diag_s[row] = 0.0625f * s;
  }
  const int g = lane >> 4, c = lane & 15;
  const int wr = w >> 1, wc = w & 1;
  f32x4 facc[2][4];
#pragma unroll
  for (int i = 0; i < 2; ++i)
#pragma unroll
    for (int j = 0; j < 4; ++j) facc[i][j] = f32x4{0.f,0.f,0.f,0.f};
#pragma unroll
  for (int kk = 0; kk < 2; ++kk) {
    half8 av[2], bv[4];
#pragma unroll
    for (int i = 0; i < 2; ++i) av[i] = *(const half8*)(qs + (wr*32 + i*16 + c)*64 + kk*32 + g*8);
#pragma unroll
    for (int j = 0; j < 4; ++j) bv[j] = *(const half8*)(ps + (wc*64 + j*16 + c)*64 + kk*32 + g*8);
#pragma unroll
    for (int i = 0; i < 2; ++i)
#pragma unroll
      for (int j = 0; j < 4; ++j)
        facc[i][j] = __builtin_amdgcn_mfma_f32_16x16x32_f16(av[i], bv[j], facc[i][j], 0, 0, 0);
  }
#pragma unroll
  for (int i = 0; i < 2; ++i)
#pragma unroll
    for (int j = 0; j < 4; ++j)
#pragma unroll
      for (int r = 0; r < 4; ++r)
        dd[(wr*32 + i*16 + g*4 + r)*129 + wc*64 + j*16 + c] = facc[i][j][r];
  __syncthreads();
}

__global__ __launch_bounds__(256) void k_kfeat(const f16* __restrict__ Kin, const f16* __restrict__ PROJF,
    f16* __restrict__ KPT, float* __restrict__ KSP)
{
  __shared__ f16 qs[64*64];
  __shared__ f16 ps[128*64];
  __shared__ float dd[64*129];
  __shared__ float diag_s[64];
  const int t = threadIdx.x;
  const int lb = blockIdx.x, bh = blockIdx.y;
  const int b = bh / 12, h = bh - b*12;
  feat_common(Kin + ((size_t)(b*4096 + lb*64))*768 + h*64, PROJF, qs, ps, dd, diag_s);
  const int l = t >> 2, s = t & 3;
  float v[32];
#pragma unroll
  for (int j = 0; j < 32; ++j) v[j] = dd[l*129 + s*32 + j];
  float mx = v[0];
#pragma unroll
  for (int j = 1; j < 32; ++j) mx = fmaxf(mx, v[j]);
  mx = fmaxf(mx, __shfl_xor(mx, 1));
  mx = fmaxf(mx, __shfl_xor(mx, 2));
  const float off = diag_s[l] + mx;
#pragma unroll
  for (int j = 0; j < 32; ++j) dd[l*129 + s*32 + j] = RATIO * (__expf(v[j] - off) + FEPS);
  __syncthreads();
  {
    const int m = t >> 1, hf = t & 1;
    float sm = 0.f;
#pragma unroll 8
    for (int l2 = hf*32; l2 < hf*32 + 32; ++l2) sm += dd[l2*129 + m];
    sm += __shfl_xor(sm, 1);
    if (hf == 0) KSP[((size_t)bh*64 + lb)*128 + m] = sm;
  }
  const int m = t >> 1, hf = t & 1;
  half8 ov[4];
#pragma unroll
  for (int i2 = 0; i2 < 32; ++i2) ov[i2>>3][i2&7] = (f16)dd[(hf*32 + i2)*129 + m];
  f16* dst = KPT + ((size_t)bh*128 + m)*4096 + lb*64 + hf*32;
#pragma unroll
  for (int q8 = 0; q8 < 4; ++q8) *(half8*)(dst + q8*8) = ov[q8];
}

// ---------------- kvs: [48] (128m x 64d) = k'^T @ v, chunked over L ----------------
__global__ __launch_bounds__(256) void k_kvs(const f16* __restrict__ KPT, const f16* __restrict__ VT,
    float* __restrict__ KVSP)
{
  __shared__ f16 As[128*32], Bs[64*32];
  f32x4 acc[4][2];
  const int chunk = blockIdx.x, bh = blockIdx.y;   // (8, 48)
  gemm_tile<64>(KPT + (size_t)bh*128*4096 + chunk*512, 4096,
                VT  + (size_t)bh*64*4096  + chunk*512, 4096, 512, As, Bs, acc);
  const int t = threadIdx.x, w = t>>6, lane = t&63, g = lane>>4, c = lane&15;
  const int wr = w>>1, wc = w&1;
  float* dst = KVSP + (size_t)(chunk*48 + bh)*128*64;
#pragma unroll
  for (int i = 0; i < 4; ++i) {
    const int row0 = wr*64 + i*16 + g*4;
#pragma unroll
    for (int j = 0; j < 2; ++j) {
      const int col = wc*32 + j*16 + c;
#pragma unroll
      for (int r = 0; r < 4; ++r) dst[(size_t)(row0 + r)*64 + col] = acc[i][j][r];
    }
  }
}

__global__ __launch_bounds__(256) void k_reduce(const float* __restrict__ KVSP, const float* __restrict__ KSP,
    f16* __restrict__ KVST, float* __restrict__ KS)
{
  const int i = blockIdx.x*256 + threadIdx.x;
  if (i < 48*128*64) {
    const int bh = i >> 13, md = i & 8191, m = md >> 6, d = md & 63;
    float s = 0.f;
#pragma unroll
    for (int c = 0; c < 8; ++c) s += KVSP[((size_t)(c*48 + bh)*128 + m)*64 + d];
    KVST[((size_t)bh*64 + d)*128 + m] = (f16)s;
  }
  if (i < 48*128) {
    const int bh = i >> 7, m = i & 127;
    float s = 0.f;
#pragma unroll 8
    for (int lb = 0; lb < 64; ++lb) s += KSP[((size_t)bh*64 + lb)*128 + m];
    KS[i] = s;
  }
}

// ---------------- fused q-feature + num GEMM + normalize -> ATT ----------------
__global__ __launch_bounds__(256) void k_qfn(const f16* __restrict__ Q, const f16* __restrict__ PROJF,
    const float* __restrict__ KS, const f16* __restrict__ KVST, f16* __restrict__ ATT)
{
  __shared__ f16 qs[64*64];
  __shared__ f16 ps[128*64];
  __shared__ float dd[64*129];
  __shared__ float diag_s[64];
  __shared__ float den_s[64];
  __shared__ f16 qp[64*128];
  __shared__ float ks_s[128];
  const int t = threadIdx.x;
  const int lb = blockIdx.x, bh = blockIdx.y;
  const int b = bh / 12, h = bh - b*12;
  if (t < 128) ks_s[t] = KS[bh*128 + t];
  feat_common(Q + ((size_t)(b*4096 + lb*64))*768 + h*64, PROJF, qs, ps, dd, diag_s);

  const int w = t >> 6, lane = t & 63, g16 = lane >> 4, c = lane & 15;
  const int wr = w >> 1, wc = w & 1;
  half8 bv2[2][4];
#pragma unroll
  for (int j = 0; j < 2; ++j) {
    const int d = wc*32 + j*16 + c;
#pragma unroll
    for (int kk = 0; kk < 4; ++kk)
      bv2[j][kk] = *(const half8*)(KVST + (size_t)bh*8192 + d*128 + kk*32 + g16*8);
  }

  const int l = t >> 2, s = t & 3;
  float v[32];
#pragma unroll
  for (int j = 0; j < 32; ++j) v[j] = dd[l*129 + s*32 + j];
  float mx = v[0];
#pragma unroll
  for (int j = 1; j < 32; ++j) mx = fmaxf(mx, v[j]);
  mx = fmaxf(mx, __shfl_xor(mx, 1));
  mx = fmaxf(mx, __shfl_xor(mx, 2));
  const float off = diag_s[l] + mx;
  half8 ov[4];
  float dp = 0.f;
#pragma unroll
  for (int j = 0; j < 32; ++j) {
    const float e = RATIO * (__expf(v[j] - off) + FEPS);
    ov[j>>3][j&7] = (f16)e;
    dp += e * ks_s[s*32 + j];
  }
  dp += __shfl_xor(dp, 1);
  dp += __shfl_xor(dp, 2);
  if (s == 0) den_s[l] = dp;
#pragma unroll
  for (int k = 0; k < 4; ++k)
    *(half8*)(qp + l*128 + (((4*s + k) ^ (l & 7)) << 3)) = ov[k];
  __syncthreads();

  f32x4 acc2[2][2];
#pragma unroll
  for (int i = 0; i < 2; ++i)
#pragma unroll
    for (int j = 0; j < 2; ++j) acc2[i][j] = f32x4{0.f,0.f,0.f,0.f};
#pragma unroll
  for (int kk = 0; kk < 4; ++kk) {
    half8 av2[2];
#pragma unroll
    for (int i = 0; i < 2; ++i) {
      const int l2 = wr*32 + i*16 + c;
      av2[i] = *(const half8*)(qp + l2*128 + (((kk*4 + g16) ^ (l2 & 7)) << 3));
    }
#pragma unroll
    for (int i = 0; i < 2; ++i)
#pragma unroll
      for (int j = 0; j < 2; ++j)
        acc2[i][j] = __builtin_amdgcn_mfma_f32_16x16x32_f16(av2[i], bv2[j][kk], acc2[i][j], 0, 0, 0);
  }

  f16* ep = ps;   // [64][72]
#pragma unroll
  for (int i = 0; i < 2; ++i)
#pragma unroll
    for (int j = 0; j < 2; ++j)
#pragma unroll
      for (int r = 0; r < 4; ++r) {
        const int l3 = wr*32 + i*16 + g16*4 + r;
        ep[l3*72 + wc*32 + j*16 + c] = (f16)(acc2[i][j][r] / den_s[l3]);
      }
  __syncthreads();
  const int row = t >> 2, sg = (t & 3) * 16;
  f16* dst = ATT + ((size_t)bh*4096 + lb*64 + row)*64 + sg;
  const f16* sp = ep + row*72 + sg;
  *(half8*)dst = *(const half8*)sp;
  *(half8*)(dst + 8) = *(const half8*)(sp + 8);
}

// ---------------- launcher ----------------
extern "C" void kernel_launch(void* const* d_in, const int* in_sizes, int n_in,
                              void* d_out, int out_size, void* d_ws, size_t ws_size,
                              hipStream_t stream)
{
  const float* x    = (const float*)d_in[0];
  const float* Wq   = (const float*)d_in[1];
  const float* bq   = (const float*)d_in[2];
  const float* Wk   = (const float*)d_in[3];
  const float* bk   = (const float*)d_in[4];
  const float* Wv   = (const float*)d_in[5];
  const float* bv   = (const float*)d_in[6];
  const float* Wo   = (const float*)d_in[7];
  const float* bo   = (const float*)d_in[8];
  const float* proj = (const float*)d_in[9];
  float* out = (float*)d_out;
  char* ws = (char*)d_ws;

  f16*   WQKVT = (f16*)(ws + OFF_WQKVT);
  f16*   WOT   = (f16*)(ws + OFF_WOT);
  f16*   PROJF = (f16*)(ws + OFF_PROJF);
  float* KS    = (float*)(ws + OFF_KS);
  float* KSP   = (float*)(ws + OFF_KSP);
  f16*   KVST  = (f16*)(ws + OFF_KVST);
  float* KVSP  = (float*)(ws + OFF_KVSP);
  f16*   X16   = (f16*)(ws + OFF_X16);
  f16*   ATT   = (f16*)(ws + OFF_ATT);
  f16*   Q16   = (f16*)(ws + OFF_Q16);
  f16*   K16   = (f16*)(ws + OFF_K16);
  f16*   VT    = (f16*)(ws + OFF_VT);
  f16*   KPT   = (f16*)(ws + OFF_KPT);

  k_prep<<<12864, 256, 0, stream>>>(x, X16, proj, PROJF, Wq, Wk, Wv, Wo, WQKVT, WOT);
  k_gemm_qkv9<<<1152, 256, 0, stream>>>(X16, WQKVT, bq, bk, bv, Q16, K16, VT);
  k_kfeat<<<dim3(64,48), 256, 0, stream>>>(K16, PROJF, KPT, KSP);
  k_kvs<<<dim3(8,48), 256, 0, stream>>>(KPT, VT, KVSP);
  k_reduce<<<1536, 256, 0, stream>>>(KVSP, KSP, KVST, KS);
  k_qfn<<<dim3(64,48), 256, 0, stream>>>(Q16, PROJF, KS, KVST, ATT);
  k_gemm_out8<<<256, 512, 0, stream>>>(ATT, WOT, bo, out);
}